// Round 1
// 478.752 us; speedup vs baseline: 1.0373x; 1.0373x over previous
//
#include <hip/hip_runtime.h>
#include <stdint.h>

#define K_DIM 512
#define N_OUT 512
#define BM 128
#define BN 128
#define BK 64

typedef __bf16 bf16x8 __attribute__((ext_vector_type(8)));
typedef float f32x4 __attribute__((ext_vector_type(4)));
typedef unsigned short ushort8 __attribute__((ext_vector_type(8)));

__device__ inline unsigned short f2bf(float f) {
  unsigned u = __float_as_uint(f);
  u += 0x7fffu + ((u >> 16) & 1u);
  return (unsigned short)(u >> 16);
}

// ---------------- W fp32 -> bf16 conversion into workspace (1 MB, ~3 us) --------
__global__ __launch_bounds__(256) void cvt_bf16_kernel(const float* __restrict__ src,
                                                       unsigned short* __restrict__ dst,
                                                       int n8) {
  int i = blockIdx.x * 256 + threadIdx.x;
  if (i >= n8) return;
  const float4* s = (const float4*)src + (size_t)i * 2;
  float4 a = s[0], c = s[1];
  ushort8 o;
  o[0] = f2bf(a.x); o[1] = f2bf(a.y); o[2] = f2bf(a.z); o[3] = f2bf(a.w);
  o[4] = f2bf(c.x); o[5] = f2bf(c.y); o[6] = f2bf(c.z); o[7] = f2bf(c.w);
  *(ushort8*)(dst + (size_t)i * 8) = o;
}

// ---------------- scatter pre-pass: s[col[e]] += x[e,0] -------------------------
__global__ __launch_bounds__(256) void zero_f32_kernel(float* __restrict__ p, int n) {
  int i = blockIdx.x * 256 + threadIdx.x;
  if (i < n) p[i] = 0.f;
}

__global__ __launch_bounds__(256) void scatter_s_kernel(const float* __restrict__ x,
                                                        const int* __restrict__ ei,
                                                        float* __restrict__ s, int E) {
  int e = blockIdx.x * 256 + threadIdx.x;
  if (e < E) {
    int c = ei[E + e];  // edge_index row 1 (int32 in practice: JAX default x64=off)
    atomicAdd(s + c, x[(size_t)e * K_DIM]);
  }
}

// ---------------- fused GEMM: A staged f32->bf16 in-kernel, B via global_load_lds,
//                  epilogue bias+relu+scatter-add, nontemporal C stores -----------
__global__ __launch_bounds__(256) void gemm_fused2_kernel(
    const float* __restrict__ x, const unsigned short* __restrict__ wb,
    const float* __restrict__ b, const float* __restrict__ s,
    float* __restrict__ out, int M) {
  __shared__ __align__(16) unsigned short Als[BM * BK];  // 16 KB
  __shared__ __align__(16) unsigned short Bls[BN * BK];  // 16 KB

  const int tid = threadIdx.x;
  const int lane = tid & 63;
  const int quad = lane >> 4;
  const int l16 = lane & 15;
  const int waveId = tid >> 6;
  const int wm = (waveId >> 1) * 64;
  const int wn = (waveId & 1) * 64;

  // XCD-aware bijective remap (m204): 4 column-tiles sharing an x row-band become
  // consecutive within one XCD -> its L2 serves the f32 x re-reads.
  const int nwg = gridDim.x * gridDim.y;     // 3128 for M=100000
  int raw = blockIdx.y * gridDim.x + blockIdx.x;
  int q = nwg >> 3, r = nwg & 7;
  int xcd = raw & 7;
  int wg = (xcd < r ? xcd * (q + 1) : r * (q + 1) + (xcd - r) * q) + (raw >> 3);
  const int blockM = (wg >> 2) * BM;         // gridDim.x == N_OUT/BN == 4
  const int blockN = (wg & 3) * BN;

  // staging assignment: thread handles LDS 16B-chunk ch = i*256+tid (lane-contiguous
  // per wave, as global_load_lds requires for B); global source chunk is XOR-swizzled
  // so fragment ds_read_b128 spreads across all 32 banks. A uses the SAME layout but
  // reg-staged (f32 load -> cvt -> ds_write_b128 to linear chunk position).
  size_t goffA[4], goffB[4];
  int ldsoff[4];
#pragma unroll
  for (int i = 0; i < 4; ++i) {
    int ch = i * 256 + tid;
    int row = ch >> 3;       // 0..127
    int c8 = ch & 7;         // 16B chunk within 128B row (bf16) / 32B (f32)
    int sc = c8 ^ (row & 7); // swizzled global chunk
    int ga_row = blockM + row;
    if (ga_row > M - 1) ga_row = M - 1;  // clamp tail (results masked in epilogue)
    goffA[i] = (size_t)ga_row * K_DIM + sc * 8;  // f32 element offset
    goffB[i] = (size_t)(blockN + row) * K_DIM + sc * 8;  // bf16 element offset
    ldsoff[i] = ch * 8;  // elements; *2B = ch*16 bytes
  }

  f32x4 acc[4][4] = {};

  for (int k0 = 0; k0 < K_DIM; k0 += BK) {
    // A: f32 -> regs (2x float4 per chunk)
    float4 a0[4], a1[4];
#pragma unroll
    for (int i = 0; i < 4; ++i) {
      a0[i] = *(const float4*)(x + goffA[i] + k0);
      a1[i] = *(const float4*)(x + goffA[i] + k0 + 4);
    }
    // B: async direct-to-LDS (bf16, pre-converted W)
#pragma unroll
    for (int i = 0; i < 4; ++i) {
      __builtin_amdgcn_global_load_lds(
          (const __attribute__((address_space(1))) void*)(wb + goffB[i] + k0),
          (__attribute__((address_space(3))) void*)(&Bls[ldsoff[i]]), 16, 0, 0);
    }
    // A: cvt + LDS write
#pragma unroll
    for (int i = 0; i < 4; ++i) {
      ushort8 o;
      o[0] = f2bf(a0[i].x); o[1] = f2bf(a0[i].y); o[2] = f2bf(a0[i].z); o[3] = f2bf(a0[i].w);
      o[4] = f2bf(a1[i].x); o[5] = f2bf(a1[i].y); o[6] = f2bf(a1[i].z); o[7] = f2bf(a1[i].w);
      *(ushort8*)(&Als[ldsoff[i]]) = o;
    }
    __syncthreads();

#pragma unroll
    for (int ss = 0; ss < 2; ++ss) {  // two K=32 steps within BK=64
      bf16x8 af[4], bfr[4];
#pragma unroll
      for (int mi = 0; mi < 4; ++mi) {
        int rr = wm + mi * 16 + l16;
        int c = (ss * 4 + quad) ^ (rr & 7);
        af[mi] = *(const bf16x8*)(&Als[rr * BK + c * 8]);
      }
#pragma unroll
      for (int ni = 0; ni < 4; ++ni) {
        int rr = wn + ni * 16 + l16;
        int c = (ss * 4 + quad) ^ (rr & 7);
        bfr[ni] = *(const bf16x8*)(&Bls[rr * BK + c * 8]);
      }
#pragma unroll
      for (int mi = 0; mi < 4; ++mi)
#pragma unroll
        for (int ni = 0; ni < 4; ++ni)
          acc[mi][ni] = __builtin_amdgcn_mfma_f32_16x16x32_bf16(af[mi], bfr[ni], acc[mi][ni], 0, 0, 0);
    }
    __syncthreads();
  }

  // epilogue: bias + relu + scatter-add (col 0 only); C/D layout col=lane&15,
  // row=quad*4+reg (m89/m91). Nontemporal: out is never re-read; keep x in L2/L3.
#pragma unroll
  for (int ni = 0; ni < 4; ++ni) {
    int gcol = blockN + wn + ni * 16 + l16;
    float bias = b[gcol];
#pragma unroll
    for (int mi = 0; mi < 4; ++mi) {
#pragma unroll
      for (int rr = 0; rr < 4; ++rr) {
        int grow = blockM + wm + mi * 16 + quad * 4 + rr;
        if (grow < M) {
          float v = acc[mi][ni][rr] + bias;
          v = v > 0.f ? v : 0.f;
          if (gcol == 0) v += s[grow];  // relu first, then scatter-add (matches ref)
          __builtin_nontemporal_store(v, out + (size_t)grow * N_OUT + gcol);
        }
      }
    }
  }
}

// ---------------- fallback: round-1 fused-conversion GEMM (if ws too small) ------
#define LDS_STRIDE 40
__global__ __launch_bounds__(256) void gemm_fused_kernel(
    const float* __restrict__ x, const float* __restrict__ W,
    const float* __restrict__ b, float* __restrict__ out, int M) {
  __shared__ __align__(16) unsigned short Als[BM * LDS_STRIDE];
  __shared__ __align__(16) unsigned short Bls[BN * LDS_STRIDE];
  const int tid = threadIdx.x;
  const int lane = tid & 63;
  const int quad = lane >> 4;
  const int l16 = lane & 15;
  const int waveId = tid >> 6;
  const int wm = (waveId >> 1) * 64;
  const int wn = (waveId & 1) * 64;
  const int blockM = blockIdx.y * BM;
  const int blockN = blockIdx.x * BN;
  f32x4 acc[4][4] = {};
  for (int k0 = 0; k0 < K_DIM; k0 += 32) {
#pragma unroll
    for (int i = 0; i < 4; ++i) {
      int idx = i * 256 + tid;
      int row = idx >> 3;
      int c4 = idx & 7;
      float4 va = make_float4(0.f, 0.f, 0.f, 0.f);
      int grow = blockM + row;
      if (grow < M) va = *(const float4*)(x + (size_t)grow * K_DIM + k0 + c4 * 4);
      ushort4 ha;
      ha.x = f2bf(va.x); ha.y = f2bf(va.y); ha.z = f2bf(va.z); ha.w = f2bf(va.w);
      *(ushort4*)(&Als[row * LDS_STRIDE + c4 * 4]) = ha;
      float4 vb = *(const float4*)(W + (size_t)(blockN + row) * K_DIM + k0 + c4 * 4);
      ushort4 hb;
      hb.x = f2bf(vb.x); hb.y = f2bf(vb.y); hb.z = f2bf(vb.z); hb.w = f2bf(vb.w);
      *(ushort4*)(&Bls[row * LDS_STRIDE + c4 * 4]) = hb;
    }
    __syncthreads();
    bf16x8 af[4], bfr[4];
#pragma unroll
    for (int mi = 0; mi < 4; ++mi)
      af[mi] = *(const bf16x8*)(&Als[(wm + mi * 16 + l16) * LDS_STRIDE + quad * 8]);
#pragma unroll
    for (int ni = 0; ni < 4; ++ni)
      bfr[ni] = *(const bf16x8*)(&Bls[(wn + ni * 16 + l16) * LDS_STRIDE + quad * 8]);
#pragma unroll
    for (int mi = 0; mi < 4; ++mi)
#pragma unroll
      for (int ni = 0; ni < 4; ++ni)
        acc[mi][ni] = __builtin_amdgcn_mfma_f32_16x16x32_bf16(af[mi], bfr[ni], acc[mi][ni], 0, 0, 0);
    __syncthreads();
  }
#pragma unroll
  for (int ni = 0; ni < 4; ++ni) {
    int gcol = blockN + wn + ni * 16 + l16;
    float bias = b[gcol];
#pragma unroll
    for (int mi = 0; mi < 4; ++mi) {
#pragma unroll
      for (int rr = 0; rr < 4; ++rr) {
        int grow = blockM + wm + mi * 16 + quad * 4 + rr;
        if (grow < M) {
          float v = acc[mi][ni][rr] + bias;
          out[(size_t)grow * N_OUT + gcol] = v > 0.f ? v : 0.f;
        }
      }
    }
  }
}

// fallback scatter: out[col[e], 0] += x[e, 0]
__global__ void scatter_kernel(const float* __restrict__ x,
                               const int* __restrict__ ei,
                               float* __restrict__ out, int E) {
  int e = blockIdx.x * 256 + threadIdx.x;
  if (e < E) {
    int c = ei[E + e];
    atomicAdd(out + (size_t)c * N_OUT, x[(size_t)e * K_DIM]);
  }
}

extern "C" void kernel_launch(void* const* d_in, const int* in_sizes, int n_in,
                              void* d_out, int out_size, void* d_ws, size_t ws_size,
                              hipStream_t stream) {
  const float* x = (const float*)d_in[0];
  const int* ei = (const int*)d_in[1];
  const float* W = (const float*)d_in[2];
  const float* b = (const float*)d_in[3];
  float* out = (float*)d_out;

  int M = in_sizes[0] / K_DIM;  // 100000
  int E = in_sizes[1] / 2;      // 100000

  size_t w_elems = (size_t)N_OUT * K_DIM;            // 262,144
  size_t need = w_elems * 2 + (size_t)M * 4 + 64;    // wb (bf16) + s (f32)

  dim3 grid(N_OUT / BN, (M + BM - 1) / BM);  // (4, 782) -> nwg=3128, %8==0

  if (ws_size >= need) {
    unsigned short* wb = (unsigned short*)d_ws;
    float* s = (float*)((char*)d_ws + w_elems * 2);  // 512 KB offset, 16B aligned
    int n8w = (int)(w_elems / 8);  // 32,768
    zero_f32_kernel<<<(M + 255) / 256, 256, 0, stream>>>(s, M);
    scatter_s_kernel<<<(E + 255) / 256, 256, 0, stream>>>(x, ei, s, E);
    cvt_bf16_kernel<<<(n8w + 255) / 256, 256, 0, stream>>>(W, wb, n8w);
    gemm_fused2_kernel<<<grid, 256, 0, stream>>>(x, wb, b, s, out, M);
  } else {
    gemm_fused_kernel<<<grid, 256, 0, stream>>>(x, W, b, out, M);
    scatter_kernel<<<(E + 255) / 256, 256, 0, stream>>>(x, ei, out, E);
  }
}

// Round 2
// 475.960 us; speedup vs baseline: 1.0434x; 1.0059x over previous
//
#include <hip/hip_runtime.h>
#include <stdint.h>

#define K_DIM 512
#define N_OUT 512
#define BM 128
#define BN 128
#define BK 64

typedef __bf16 bf16x8 __attribute__((ext_vector_type(8)));
typedef float f32x4 __attribute__((ext_vector_type(4)));
typedef unsigned short ushort8 __attribute__((ext_vector_type(8)));

__device__ inline unsigned short f2bf(float f) {
  unsigned u = __float_as_uint(f);
  u += 0x7fffu + ((u >> 16) & 1u);
  return (unsigned short)(u >> 16);
}

// ---------------- prep: W fp32->bf16 + zero the scatter accumulator -------------
__global__ __launch_bounds__(256) void prep_kernel(const float* __restrict__ W,
                                                   unsigned short* __restrict__ wb,
                                                   float* __restrict__ s,
                                                   int n8w, int M) {
  int i = blockIdx.x * 256 + threadIdx.x;
  if (i < n8w) {
    const float4* sp = (const float4*)W + (size_t)i * 2;
    float4 a = sp[0], c = sp[1];
    ushort8 o;
    o[0] = f2bf(a.x); o[1] = f2bf(a.y); o[2] = f2bf(a.z); o[3] = f2bf(a.w);
    o[4] = f2bf(c.x); o[5] = f2bf(c.y); o[6] = f2bf(c.z); o[7] = f2bf(c.w);
    *(ushort8*)(wb + (size_t)i * 8) = o;
  } else {
    int j = i - n8w;
    if (j < M) s[j] = 0.f;
  }
}

// ---------------- scatter pre-pass: s[col[e]] += x[e,0] -------------------------
__global__ __launch_bounds__(256) void scatter_s_kernel(const float* __restrict__ x,
                                                        const int* __restrict__ ei,
                                                        float* __restrict__ s, int E) {
  int e = blockIdx.x * 256 + threadIdx.x;
  if (e < E) {
    int c = ei[E + e];
    atomicAdd(s + c, x[(size_t)e * K_DIM]);
  }
}

// ---------------- fused GEMM, 2-phase double-buffered pipeline (T3-min) ---------
// A: f32 loaded to regs one K-tile ahead, cvt'd AFTER compute, ds_write to the
//    other buffer. B: global_load_lds issued one K-tile ahead into other buffer.
// __syncthreads' vmcnt drain lands after the compute phase, so loads have the
// whole MFMA block in flight -> latency hidden without inline asm.
__global__ __launch_bounds__(256) void gemm_fused2_kernel(
    const float* __restrict__ x, const unsigned short* __restrict__ wb,
    const float* __restrict__ b, const float* __restrict__ s,
    float* __restrict__ out, int M) {
  __shared__ __align__(16) unsigned short Als[2][BM * BK];  // 2 x 16 KB
  __shared__ __align__(16) unsigned short Bls[2][BN * BK];  // 2 x 16 KB

  const int tid = threadIdx.x;
  const int lane = tid & 63;
  const int quad = lane >> 4;
  const int l16 = lane & 15;
  const int waveId = tid >> 6;
  const int wm = (waveId >> 1) * 64;
  const int wn = (waveId & 1) * 64;

  // XCD-aware bijective remap (m204): 4 column-tiles sharing an x row-band run
  // consecutively on one XCD -> its L2/L3 slice serves the f32 x re-reads.
  const int nwg = gridDim.x * gridDim.y;  // 3128, %8==0
  int raw = blockIdx.y * gridDim.x + blockIdx.x;
  int q = nwg >> 3, r = nwg & 7;
  int xcd = raw & 7;
  int wg = (xcd < r ? xcd * (q + 1) : r * (q + 1) + (xcd - r) * q) + (raw >> 3);
  const int blockM = (wg >> 2) * BM;  // gridDim.x == N_OUT/BN == 4
  const int blockN = (wg & 3) * BN;

  // staging: thread owns LDS 16B-chunk ch = i*256+tid (lane-contiguous per wave,
  // required by global_load_lds for B); global source chunk XOR-swizzled so the
  // fragment ds_read_b128 spreads across banks.
  size_t goffA[4], goffB[4];
  int ldsoff[4];
#pragma unroll
  for (int i = 0; i < 4; ++i) {
    int ch = i * 256 + tid;
    int row = ch >> 3;
    int c8 = ch & 7;
    int sc = c8 ^ (row & 7);
    int ga_row = blockM + row;
    if (ga_row > M - 1) ga_row = M - 1;  // clamp tail (masked in epilogue)
    goffA[i] = (size_t)ga_row * K_DIM + sc * 8;           // f32 elements
    goffB[i] = (size_t)(blockN + row) * K_DIM + sc * 8;   // bf16 elements
    ldsoff[i] = ch * 8;
  }

  f32x4 acc[4][4] = {};
  float4 a0[4], a1[4];

  // ---- prologue: stage K-tile 0 into buffer 0 ----
#pragma unroll
  for (int i = 0; i < 4; ++i) {
    __builtin_amdgcn_global_load_lds(
        (const __attribute__((address_space(1))) void*)(wb + goffB[i]),
        (__attribute__((address_space(3))) void*)(&Bls[0][ldsoff[i]]), 16, 0, 0);
    a0[i] = *(const float4*)(x + goffA[i]);
    a1[i] = *(const float4*)(x + goffA[i] + 4);
  }
#pragma unroll
  for (int i = 0; i < 4; ++i) {
    ushort8 o;
    o[0] = f2bf(a0[i].x); o[1] = f2bf(a0[i].y); o[2] = f2bf(a0[i].z); o[3] = f2bf(a0[i].w);
    o[4] = f2bf(a1[i].x); o[5] = f2bf(a1[i].y); o[6] = f2bf(a1[i].z); o[7] = f2bf(a1[i].w);
    *(ushort8*)(&Als[0][ldsoff[i]]) = o;
  }
  __syncthreads();

  int cur = 0;
  for (int k0 = 0; k0 < K_DIM; k0 += BK) {
    const int nxt = cur ^ 1;
    const bool has_next = (k0 + BK) < K_DIM;

    // 0/1. issue next tile's loads (async B -> LDS[nxt]; A f32 -> regs)
    if (has_next) {
#pragma unroll
      for (int i = 0; i < 4; ++i) {
        __builtin_amdgcn_global_load_lds(
            (const __attribute__((address_space(1))) void*)(wb + goffB[i] + k0 + BK),
            (__attribute__((address_space(3))) void*)(&Bls[nxt][ldsoff[i]]), 16, 0, 0);
      }
#pragma unroll
      for (int i = 0; i < 4; ++i) {
        a0[i] = *(const float4*)(x + goffA[i] + k0 + BK);
        a1[i] = *(const float4*)(x + goffA[i] + k0 + BK + 4);
      }
    }

    // 2. compute on buffer[cur] while next-tile loads fly
#pragma unroll
    for (int ss = 0; ss < 2; ++ss) {
      bf16x8 af[4], bfr[4];
#pragma unroll
      for (int mi = 0; mi < 4; ++mi) {
        int rr = wm + mi * 16 + l16;
        int c = (ss * 4 + quad) ^ (rr & 7);
        af[mi] = *(const bf16x8*)(&Als[cur][rr * BK + c * 8]);
      }
#pragma unroll
      for (int ni = 0; ni < 4; ++ni) {
        int rr = wn + ni * 16 + l16;
        int c = (ss * 4 + quad) ^ (rr & 7);
        bfr[ni] = *(const bf16x8*)(&Bls[cur][rr * BK + c * 8]);
      }
#pragma unroll
      for (int mi = 0; mi < 4; ++mi)
#pragma unroll
        for (int ni = 0; ni < 4; ++ni)
          acc[mi][ni] = __builtin_amdgcn_mfma_f32_16x16x32_bf16(af[mi], bfr[ni], acc[mi][ni], 0, 0, 0);
    }

    // 3/4. cvt + write next A tile into buffer[nxt] (disjoint from readers of cur)
    if (has_next) {
#pragma unroll
      for (int i = 0; i < 4; ++i) {
        ushort8 o;
        o[0] = f2bf(a0[i].x); o[1] = f2bf(a0[i].y); o[2] = f2bf(a0[i].z); o[3] = f2bf(a0[i].w);
        o[4] = f2bf(a1[i].x); o[5] = f2bf(a1[i].y); o[6] = f2bf(a1[i].z); o[7] = f2bf(a1[i].w);
        *(ushort8*)(&Als[nxt][ldsoff[i]]) = o;
      }
    }

    // 5. barrier (drains vmcnt/lgkmcnt — loads had the whole compute to land)
    __syncthreads();
    cur = nxt;
  }

  // epilogue: bias + relu + scatter-add (col 0); C/D layout col=lane&15,
  // row=quad*4+reg (m89/m91). Nontemporal: out never re-read; keep x in caches.
#pragma unroll
  for (int ni = 0; ni < 4; ++ni) {
    int gcol = blockN + wn + ni * 16 + l16;
    float bias = b[gcol];
#pragma unroll
    for (int mi = 0; mi < 4; ++mi) {
#pragma unroll
      for (int rr = 0; rr < 4; ++rr) {
        int grow = blockM + wm + mi * 16 + quad * 4 + rr;
        if (grow < M) {
          float v = acc[mi][ni][rr] + bias;
          v = v > 0.f ? v : 0.f;
          if (gcol == 0) v += s[grow];  // relu first, then scatter-add (matches ref)
          __builtin_nontemporal_store(v, out + (size_t)grow * N_OUT + gcol);
        }
      }
    }
  }
}

// ---------------- fallback: round-1 fused-conversion GEMM (if ws too small) ------
#define LDS_STRIDE 40
__global__ __launch_bounds__(256) void gemm_fused_kernel(
    const float* __restrict__ x, const float* __restrict__ W,
    const float* __restrict__ b, float* __restrict__ out, int M) {
  __shared__ __align__(16) unsigned short Als[BM * LDS_STRIDE];
  __shared__ __align__(16) unsigned short Bls[BN * LDS_STRIDE];
  const int tid = threadIdx.x;
  const int lane = tid & 63;
  const int quad = lane >> 4;
  const int l16 = lane & 15;
  const int waveId = tid >> 6;
  const int wm = (waveId >> 1) * 64;
  const int wn = (waveId & 1) * 64;
  const int blockM = blockIdx.y * BM;
  const int blockN = blockIdx.x * BN;
  f32x4 acc[4][4] = {};
  for (int k0 = 0; k0 < K_DIM; k0 += 32) {
#pragma unroll
    for (int i = 0; i < 4; ++i) {
      int idx = i * 256 + tid;
      int row = idx >> 3;
      int c4 = idx & 7;
      float4 va = make_float4(0.f, 0.f, 0.f, 0.f);
      int grow = blockM + row;
      if (grow < M) va = *(const float4*)(x + (size_t)grow * K_DIM + k0 + c4 * 4);
      ushort4 ha;
      ha.x = f2bf(va.x); ha.y = f2bf(va.y); ha.z = f2bf(va.z); ha.w = f2bf(va.w);
      *(ushort4*)(&Als[row * LDS_STRIDE + c4 * 4]) = ha;
      float4 vb = *(const float4*)(W + (size_t)(blockN + row) * K_DIM + k0 + c4 * 4);
      ushort4 hb;
      hb.x = f2bf(vb.x); hb.y = f2bf(vb.y); hb.z = f2bf(vb.z); hb.w = f2bf(vb.w);
      *(ushort4*)(&Bls[row * LDS_STRIDE + c4 * 4]) = hb;
    }
    __syncthreads();
    bf16x8 af[4], bfr[4];
#pragma unroll
    for (int mi = 0; mi < 4; ++mi)
      af[mi] = *(const bf16x8*)(&Als[(wm + mi * 16 + l16) * LDS_STRIDE + quad * 8]);
#pragma unroll
    for (int ni = 0; ni < 4; ++ni)
      bfr[ni] = *(const bf16x8*)(&Bls[(wn + ni * 16 + l16) * LDS_STRIDE + quad * 8]);
#pragma unroll
    for (int mi = 0; mi < 4; ++mi)
#pragma unroll
      for (int ni = 0; ni < 4; ++ni)
        acc[mi][ni] = __builtin_amdgcn_mfma_f32_16x16x32_bf16(af[mi], bfr[ni], acc[mi][ni], 0, 0, 0);
    __syncthreads();
  }
#pragma unroll
  for (int ni = 0; ni < 4; ++ni) {
    int gcol = blockN + wn + ni * 16 + l16;
    float bias = b[gcol];
#pragma unroll
    for (int mi = 0; mi < 4; ++mi) {
#pragma unroll
      for (int rr = 0; rr < 4; ++rr) {
        int grow = blockM + wm + mi * 16 + quad * 4 + rr;
        if (grow < M) {
          float v = acc[mi][ni][rr] + bias;
          out[(size_t)grow * N_OUT + gcol] = v > 0.f ? v : 0.f;
        }
      }
    }
  }
}

// fallback scatter: out[col[e], 0] += x[e, 0]
__global__ void scatter_kernel(const float* __restrict__ x,
                               const int* __restrict__ ei,
                               float* __restrict__ out, int E) {
  int e = blockIdx.x * 256 + threadIdx.x;
  if (e < E) {
    int c = ei[E + e];
    atomicAdd(out + (size_t)c * N_OUT, x[(size_t)e * K_DIM]);
  }
}

extern "C" void kernel_launch(void* const* d_in, const int* in_sizes, int n_in,
                              void* d_out, int out_size, void* d_ws, size_t ws_size,
                              hipStream_t stream) {
  const float* x = (const float*)d_in[0];
  const int* ei = (const int*)d_in[1];
  const float* W = (const float*)d_in[2];
  const float* b = (const float*)d_in[3];
  float* out = (float*)d_out;

  int M = in_sizes[0] / K_DIM;  // 100000
  int E = in_sizes[1] / 2;      // 100000

  size_t w_elems = (size_t)N_OUT * K_DIM;            // 262,144
  size_t need = w_elems * 2 + (size_t)M * 4 + 64;    // wb (bf16) + s (f32)

  dim3 grid(N_OUT / BN, (M + BM - 1) / BM);  // (4, 782) -> nwg=3128, %8==0

  if (ws_size >= need) {
    unsigned short* wb = (unsigned short*)d_ws;
    float* s = (float*)((char*)d_ws + w_elems * 2);  // 512 KB offset, 16B aligned
    int n8w = (int)(w_elems / 8);  // 32,768
    int prep_total = n8w + M;
    prep_kernel<<<(prep_total + 255) / 256, 256, 0, stream>>>(W, wb, s, n8w, M);
    scatter_s_kernel<<<(E + 255) / 256, 256, 0, stream>>>(x, ei, s, E);
    gemm_fused2_kernel<<<grid, 256, 0, stream>>>(x, wb, b, s, out, M);
  } else {
    gemm_fused_kernel<<<grid, 256, 0, stream>>>(x, W, b, out, M);
    scatter_kernel<<<(E + 255) / 256, 256, 0, stream>>>(x, ei, out, E);
  }
}